// Round 5
// baseline (1355.369 us; speedup 1.0000x reference)
//
#include <hip/hip_runtime.h>

#define BSZ 16384

typedef __attribute__((ext_vector_type(8))) short bf16x8;
typedef __attribute__((ext_vector_type(4))) float f32x4;

__device__ inline unsigned short f2bf(float x) {
    unsigned u = __float_as_uint(x);
    u += 0x7fffu + ((u >> 16) & 1u);
    return (unsigned short)(u >> 16);
}
__device__ inline float bf2f(unsigned short h) {
    return __uint_as_float(((unsigned)h) << 16);
}

// async global->LDS, 16B per lane; l must be wave-uniform base (lane*16 added by HW)
__device__ inline void gld16(const void* g, void* l) {
    __builtin_amdgcn_global_load_lds((const __attribute__((address_space(1))) unsigned*)g,
                                     (__attribute__((address_space(3))) unsigned*)l, 16, 0, 0);
}

// ---------------- prep: fp32 -> separate hi/lo bf16 planes ----------------
struct PrepArgs {
    const float* src[26];
    unsigned short* dsth[26];
    unsigned short* dstl[26];
    int start[26];   // prefix (elements); all sizes multiples of 1024
    int nseg;
};
__global__ __launch_bounds__(256) void prep_kernel(PrepArgs pa) {
    const int base = blockIdx.x << 10;
    int seg = 0;
    #pragma unroll 1
    for (int i = 0; i < 25; ++i)
        if (seg + 1 < pa.nseg && base >= pa.start[seg + 1]) seg++;
    const int off = base - pa.start[seg] + (threadIdx.x << 2);
    const float4 v = *(const float4*)(pa.src[seg] + off);
    ushort4 h, l;
    h.x = f2bf(v.x); h.y = f2bf(v.y); h.z = f2bf(v.z); h.w = f2bf(v.w);
    l.x = f2bf(v.x - bf2f(h.x)); l.y = f2bf(v.y - bf2f(h.y));
    l.z = f2bf(v.z - bf2f(h.z)); l.w = f2bf(v.w - bf2f(h.w));
    *(ushort4*)(pa.dsth[seg] + off) = h;
    *(ushort4*)(pa.dstl[seg] + off) = l;
}

// ---------------- codebook norms (all 3 levels, fp32 inputs) ----------------
__global__ __launch_bounds__(256) void cb_norms3(
    const float* __restrict__ c0, const float* __restrict__ c1,
    const float* __restrict__ c2, float* __restrict__ cbn)
{
    const int r = blockIdx.x * 256 + threadIdx.x;   // 0..10239
    const float* src; int off;
    if (r < 2048) { src = c0; off = r; }
    else if (r < 6144) { src = c1; off = r - 2048; }
    else { src = c2; off = r - 6144; }
    const float4* p = (const float4*)(src + (size_t)off * 64);
    float s = 0.f;
    #pragma unroll
    for (int c = 0; c < 16; ++c) {
        float4 v = p[c];
        s += v.x * v.x + v.y * v.y + v.z * v.z + v.w * v.w;
    }
    cbn[r] = s;
}

// ---------------- attention fold: W_comb = ow@wv (hi plane), b_comb = ow@bv + ob ----
__global__ __launch_bounds__(256) void attn_combine(
    const float* __restrict__ iw, const float* __restrict__ ib,
    const float* __restrict__ ow, const float* __restrict__ ob,
    unsigned short* __restrict__ wch, float* __restrict__ bcomb)
{
    __shared__ float o[4096], v[4096];
    const float* wv = iw + 128 * 64;
    for (int t = threadIdx.x; t < 4096; t += 256) { o[t] = ow[t]; v[t] = wv[t]; }
    __syncthreads();
    for (int t = threadIdx.x; t < 4096; t += 256) {
        const int j = t >> 6, i = t & 63;
        float s = 0.f;
        #pragma unroll
        for (int k = 0; k < 64; ++k) s += o[j * 64 + k] * v[k * 64 + i];
        wch[t] = f2bf(s);
    }
    if (threadIdx.x < 64) {
        const int j = threadIdx.x;
        const float* bv = ib + 128;
        float s = ob[j];
        #pragma unroll
        for (int k = 0; k < 64; ++k) s += o[j * 64 + k] * bv[k];
        bcomb[j] = s;
    }
}

// ---------------- batched MFMA GEMM, m97-style staging, separate planes ----------
// Per z: C = act(A @ W^T + bias). BM=128, BK=32, BN in {64,128}.
// OUT: 0 = f32, 1 = hi+lo planes, 2 = hi plane only.
struct GemmB {
    const unsigned short* Ah[3]; const unsigned short* Al[3];
    const unsigned short* Wh[3]; const unsigned short* Wl[3];
    const float* bias[3];
    float* Cf[3]; unsigned short* Ch[3]; unsigned short* Cl[3];
};
template<int SPLIT, int BN, int OUT>
__global__ __launch_bounds__(256) void gemm4(GemmB g, int M, int N, int K, int relu)
{
    constexpr int MT = (BN == 128) ? 4 : 2;
    constexpr int ASZ = 128 * 32, WSZ = BN * 32;
    __shared__ __align__(16) unsigned short lds[(1 + SPLIT) * (ASZ + WSZ)];
    unsigned short* sAh = lds;
    unsigned short* sAl = lds + ASZ;                  // SPLIT only
    unsigned short* sWh = lds + (1 + SPLIT) * ASZ;
    unsigned short* sWl = sWh + WSZ;                  // SPLIT only
    const int z = blockIdx.z;
    const unsigned short* Ah = g.Ah[z]; const unsigned short* Al = g.Al[z];
    const unsigned short* Wh = g.Wh[z]; const unsigned short* Wl = g.Wl[z];
    const float* bias = g.bias[z];
    const int tid = threadIdx.x, lane = tid & 63, wv = tid >> 6;
    const int q = lane >> 4, c16 = lane & 15;
    const int m0 = blockIdx.y << 7, n0 = blockIdx.x * BN;
    const int wm = (BN == 128) ? (wv >> 1) : wv;
    const int wn = (BN == 128) ? (wv & 1) : 0;
    const int wbase = tid & 192;

    f32x4 acc[MT][4] = {};

    for (int k0 = 0; k0 < K; k0 += 32) {
        __syncthreads();
        #pragma unroll
        for (int i = 0; i < 2; ++i) {      // A: 512 16B-chunks
            const int ch = (i << 8) + tid;
            const int row = ch >> 2, col = (ch & 3) << 3;
            const size_t gofs = (size_t)(m0 + row) * K + k0 + col;
            const int lofs = ((i << 8) + wbase) << 3;
            gld16(Ah + gofs, sAh + lofs);
            if (SPLIT) gld16(Al + gofs, sAl + lofs);
        }
        #pragma unroll
        for (int i = 0; i < BN / 64; ++i) { // W: BN*4 16B-chunks
            const int ch = (i << 8) + tid;
            const int row = ch >> 2, col = (ch & 3) << 3;
            const size_t gofs = (size_t)(n0 + row) * K + k0 + col;
            const int lofs = ((i << 8) + wbase) << 3;
            gld16(Wh + gofs, sWh + lofs);
            if (SPLIT) gld16(Wl + gofs, sWl + lofs);
        }
        __syncthreads();

        bf16x8 fah[MT], fal[MT], fbh[4], fbl[4];
        #pragma unroll
        for (int mt = 0; mt < MT; ++mt) {
            const int r = (BN == 128 ? wm * 64 : wv * 32) + mt * 16 + c16;
            fah[mt] = *(const bf16x8*)&sAh[r * 32 + q * 8];
            if (SPLIT) fal[mt] = *(const bf16x8*)&sAl[r * 32 + q * 8];
        }
        #pragma unroll
        for (int nt = 0; nt < 4; ++nt) {
            const int r = wn * 64 + nt * 16 + c16;
            fbh[nt] = *(const bf16x8*)&sWh[r * 32 + q * 8];
            if (SPLIT) fbl[nt] = *(const bf16x8*)&sWl[r * 32 + q * 8];
        }
        #pragma unroll
        for (int nt = 0; nt < 4; ++nt)
            #pragma unroll
            for (int mt = 0; mt < MT; ++mt) {
                acc[mt][nt] = __builtin_amdgcn_mfma_f32_16x16x32_bf16(fah[mt], fbh[nt], acc[mt][nt], 0, 0, 0);
                if (SPLIT) {
                    acc[mt][nt] = __builtin_amdgcn_mfma_f32_16x16x32_bf16(fah[mt], fbl[nt], acc[mt][nt], 0, 0, 0);
                    acc[mt][nt] = __builtin_amdgcn_mfma_f32_16x16x32_bf16(fal[mt], fbh[nt], acc[mt][nt], 0, 0, 0);
                }
            }
    }

    // epilogue: C/D layout col=lane&15, row=(lane>>4)*4+reg
    #pragma unroll
    for (int nt = 0; nt < 4; ++nt) {
        const int gcol = n0 + wn * 64 + nt * 16 + c16;
        const float bb = bias[gcol];
        #pragma unroll
        for (int mt = 0; mt < MT; ++mt)
            #pragma unroll
            for (int r = 0; r < 4; ++r) {
                const int grow = m0 + (BN == 128 ? wm * 64 : wv * 32) + mt * 16 + q * 4 + r;
                float v = acc[mt][nt][r] + bb;
                if (relu) v = fmaxf(v, 0.f);
                const size_t o = (size_t)grow * N + gcol;
                if (OUT == 0) g.Cf[z][o] = v;
                else {
                    const unsigned short h = f2bf(v);
                    g.Ch[z][o] = h;
                    if (OUT == 1) g.Cl[z][o] = f2bf(v - bf2f(h));
                }
            }
    }
}

// ---------------- VQ sweep: split-bf16 MFMA distances, f64-key argmin ----------------
// grid (256, 10): 64 samples x 1024-entry chunk; depth-2 register prefetch of cb tiles;
// key = (dist_bits << 32) | idx  ->  fmin == argmin with first-index tie-break.
struct VqB {
    const unsigned short* zh[10]; const unsigned short* zl[10];
    const unsigned short* ch[10]; const unsigned short* cl[10];
    const float* nn[10];
    int ebase[10]; int bkoff[10];
};
__global__ __launch_bounds__(256) void vq_sweep(VqB vb, unsigned long long* __restrict__ bk)
{
    __shared__ double bks[64][4];
    const int tid = threadIdx.x, lane = tid & 63, wv = tid >> 6;
    const int q = lane >> 4, c16 = lane & 15;
    const int ck = blockIdx.y;
    const size_t s0 = (size_t)blockIdx.x << 6;
    const unsigned short* zh = vb.zh[ck]; const unsigned short* zl = vb.zl[ck];
    const unsigned short* ch = vb.ch[ck]; const unsigned short* cl = vb.cl[ck];
    const float* nn = vb.nn[ck];
    const int eb = vb.ebase[ck];

    // A frags (z) in registers for the whole sweep (direct b128 plane loads)
    bf16x8 ah[4][2], al[4][2];
    #pragma unroll
    for (int mt = 0; mt < 4; ++mt)
        #pragma unroll
        for (int ks = 0; ks < 2; ++ks) {
            const size_t a = ((s0 + mt * 16 + c16) << 6) + (ks << 5) + (q << 3);
            ah[mt][ks] = *(const bf16x8*)(zh + a);
            al[mt][ks] = *(const bf16x8*)(zl + a);
        }

    double best[4][4];
    #pragma unroll
    for (int mt = 0; mt < 4; ++mt)
        #pragma unroll
        for (int r = 0; r < 4; ++r) best[mt][r] = __hiloint2double(0x7f000000, 0);

    bf16x8 bh[2][2], bl[2][2];
    float nnv[2];
    auto ldB = [&](int t, int slot) {
        const int e = eb + t * 16 + c16;
        const size_t a = ((size_t)e << 6) + (q << 3);
        bh[slot][0] = *(const bf16x8*)(ch + a);
        bh[slot][1] = *(const bf16x8*)(ch + a + 32);
        bl[slot][0] = *(const bf16x8*)(cl + a);
        bl[slot][1] = *(const bf16x8*)(cl + a + 32);
        nnv[slot] = nn[e];
    };
    ldB(wv, 0);
    ldB(wv + 4, 1);

    for (int i = 0; i < 16; ++i) {       // 16 tiles per wave, stride 4
        const int t = wv + 4 * i;
        const int cur = i & 1;
        f32x4 acc[4] = {};
        #pragma unroll
        for (int ks = 0; ks < 2; ++ks)
            #pragma unroll
            for (int mt = 0; mt < 4; ++mt) {
                acc[mt] = __builtin_amdgcn_mfma_f32_16x16x32_bf16(ah[mt][ks], bh[cur][ks], acc[mt], 0, 0, 0);
                acc[mt] = __builtin_amdgcn_mfma_f32_16x16x32_bf16(ah[mt][ks], bl[cur][ks], acc[mt], 0, 0, 0);
                acc[mt] = __builtin_amdgcn_mfma_f32_16x16x32_bf16(al[mt][ks], bh[cur][ks], acc[mt], 0, 0, 0);
            }
        const float nnc = nnv[cur];
        const int idxlo = eb + t * 16 + c16;
        #pragma unroll
        for (int mt = 0; mt < 4; ++mt)
            #pragma unroll
            for (int r = 0; r < 4; ++r) {
                const float dist = fmaf(-2.0f, acc[mt][r], nnc);
                const double key = __hiloint2double(__float_as_int(dist), idxlo);
                best[mt][r] = fmin(best[mt][r], key);
            }
        if (i < 14) ldB(t + 8, cur);     // refill consumed slot, 2 deep
    }

    // reduce over the 16 entry-lanes (xor masks < 16 stay within sample group)
    #pragma unroll
    for (int off = 1; off < 16; off <<= 1)
        #pragma unroll
        for (int mt = 0; mt < 4; ++mt)
            #pragma unroll
            for (int r = 0; r < 4; ++r)
                best[mt][r] = fmin(best[mt][r], __shfl_xor(best[mt][r], off, 64));
    if (c16 == 0)
        #pragma unroll
        for (int mt = 0; mt < 4; ++mt)
            #pragma unroll
            for (int r = 0; r < 4; ++r)
                bks[mt * 16 + q * 4 + r][wv] = best[mt][r];
    __syncthreads();
    if (tid < 64) {
        const double b = fmin(fmin(bks[tid][0], bks[tid][1]), fmin(bks[tid][2], bks[tid][3]));
        atomicMin(&bk[vb.bkoff[ck] + s0 + tid], (unsigned long long)__double_as_longlong(b));
    }
}

// ---------------- gather zq planes from final keys ----------------
__global__ __launch_bounds__(256) void gather_b(
    const unsigned long long* __restrict__ bk,
    const unsigned short* __restrict__ ch0, const unsigned short* __restrict__ cl0,
    const unsigned short* __restrict__ ch1, const unsigned short* __restrict__ cl1,
    const unsigned short* __restrict__ ch2, const unsigned short* __restrict__ cl2,
    unsigned short* __restrict__ zqh, unsigned short* __restrict__ zql)
{
    const int gid = blockIdx.x * 256 + threadIdx.x;   // 0 .. 3*B*64
    const int l = gid / (BSZ * 64);
    const int r = gid - l * (BSZ * 64);
    const int s = r >> 6, d = r & 63;
    const int idx = (int)(unsigned)(bk[(size_t)l * BSZ + s] & 0xffffffffULL);
    const unsigned short* ch = (l == 0) ? ch0 : (l == 1 ? ch1 : ch2);
    const unsigned short* cl = (l == 0) ? cl0 : (l == 1 ? cl1 : cl2);
    zqh[gid] = ch[(size_t)idx * 64 + d];
    zql[gid] = cl[(size_t)idx * 64 + d];
}

// ---------------- batched losses ----------------
__global__ __launch_bounds__(256) void loss_b(
    const unsigned short* __restrict__ zeh, const unsigned short* __restrict__ zel,
    const unsigned short* __restrict__ zqh, const unsigned short* __restrict__ zql,
    const float* __restrict__ attb, float* __restrict__ vq_out,
    float* __restrict__ commit_out, float inv)
{
    const int l = blockIdx.z;
    const size_t base = (size_t)l * BSZ * 64;
    const float* at = (l > 0) ? attb + (size_t)(l - 1) * BSZ * 64 : nullptr;
    float cs = 0.f, vs = 0.f;
    for (int t = blockIdx.x * 256 + threadIdx.x; t < BSZ * 64; t += gridDim.x * 256) {
        const float e = bf2f(zeh[base + t]) + bf2f(zel[base + t]);
        const float qv = bf2f(zqh[base + t]) + bf2f(zql[base + t]);
        const float dc = e - qv;
        cs += dc * dc;
        const float za = at ? (e + at[t]) : e;
        const float dv = qv - za;
        vs += dv * dv;
    }
    #pragma unroll
    for (int off = 32; off; off >>= 1) {
        cs += __shfl_down(cs, off, 64);
        vs += __shfl_down(vs, off, 64);
    }
    __shared__ float sc[4], sv[4];
    const int lane = threadIdx.x & 63, w = threadIdx.x >> 6;
    if (lane == 0) { sc[w] = cs; sv[w] = vs; }
    __syncthreads();
    if (threadIdx.x == 0) {
        atomicAdd(commit_out, (sc[0] + sc[1] + sc[2] + sc[3]) * inv);
        atomicAdd(vq_out, (sv[0] + sv[1] + sv[2] + sv[3]) * inv);
    }
}

extern "C" void kernel_launch(void* const* d_in, const int* in_sizes, int n_in,
                              void* d_out, int out_size, void* d_ws, size_t ws_size,
                              hipStream_t stream)
{
    const int CB_SIZES[3] = {2048, 4096, 4096};

    // ---- workspace carve-up (256B-aligned segments) ----
    char* wsp = (char*)d_ws;
    auto alloc = [&](size_t bytes) -> void* {
        void* p = wsp; wsp += (bytes + 255) & ~(size_t)255; return p;
    };
    unsigned long long* bk = (unsigned long long*)alloc((size_t)3 * BSZ * 8);
    float* ATT   = (float*)alloc((size_t)2 * BSZ * 64 * 4);
    float* cbn   = (float*)alloc(10240 * 4);
    float* bcomb = (float*)alloc(128 * 4);
    auto u16a = [&](size_t n) -> unsigned short* { return (unsigned short*)alloc(n * 2); };
    unsigned short* XH  = u16a((size_t)3 * BSZ * 512);
    unsigned short* XL  = u16a((size_t)3 * BSZ * 512);
    unsigned short* H1H = u16a((size_t)3 * BSZ * 256);
    unsigned short* H1L = u16a((size_t)3 * BSZ * 256);
    unsigned short* H2H = u16a((size_t)3 * BSZ * 256);
    unsigned short* H2L = u16a((size_t)3 * BSZ * 256);
    unsigned short* ZEH = u16a((size_t)3 * BSZ * 64);
    unsigned short* ZEL = u16a((size_t)3 * BSZ * 64);
    unsigned short* ZQH = u16a((size_t)3 * BSZ * 64);
    unsigned short* ZQL = u16a((size_t)3 * BSZ * 64);
    unsigned short* WCH = u16a(2 * 4096);
    unsigned short* WREG = u16a((size_t)2 * (3 * 425984 + 655360));

    float* out = (float*)d_out;
    float* vq_loss = out + (size_t)3 * BSZ * 512;
    float* commit  = vq_loss + 1;
    hipMemsetAsync(vq_loss, 0, 2 * sizeof(float), stream);
    hipMemsetAsync(bk, 0xFF, (size_t)3 * BSZ * 8, stream);

    // ---- prep descriptor table (x inputs + weights + codebooks) ----
    PrepArgs pa; int pos = 0, ns = 0;
    const unsigned short *ew1h[3], *ew1l[3], *ew2h[3], *ew2l[3], *ew3h[3], *ew3l[3];
    const unsigned short *dw1h[3], *dw1l[3], *dw2h[3], *dw2l[3], *dw3h[3], *dw3l[3];
    const unsigned short *cbh[3], *cbl[3];
    auto add = [&](const float* src, unsigned short* dh, unsigned short* dl, int n) {
        pa.src[ns] = src; pa.dsth[ns] = dh; pa.dstl[ns] = dl; pa.start[ns] = pos;
        pos += n; ns++;
    };
    for (int l = 0; l < 3; ++l)
        add((const float*)d_in[l], XH + (size_t)l * BSZ * 512, XL + (size_t)l * BSZ * 512, BSZ * 512);
    {
        unsigned short* wc = WREG;
        auto addw = [&](const float* src, int n, const unsigned short** ph, const unsigned short** pl) {
            add(src, wc, wc + n, n);
            *ph = wc; *pl = wc + n; wc += 2 * n;
        };
        for (int l = 0; l < 3; ++l) {
            const int base = 3 + 13 * l;
            addw((const float*)d_in[base + 0], 256 * 512, &ew1h[l], &ew1l[l]);
            addw((const float*)d_in[base + 2], 256 * 256, &ew2h[l], &ew2l[l]);
            addw((const float*)d_in[base + 4], 64 * 256,  &ew3h[l], &ew3l[l]);
            addw((const float*)d_in[base + 6], 256 * 64,  &dw1h[l], &dw1l[l]);
            addw((const float*)d_in[base + 8], 256 * 256, &dw2h[l], &dw2l[l]);
            addw((const float*)d_in[base + 10], 512 * 256, &dw3h[l], &dw3l[l]);
            addw((const float*)d_in[base + 12], CB_SIZES[l] * 64, &cbh[l], &cbl[l]);
        }
    }
    pa.nseg = ns;
    for (int i = ns; i < 26; ++i) pa.start[i] = 0x7fffffff;

    hipLaunchKernelGGL(prep_kernel, dim3(pos >> 10), dim3(256), 0, stream, pa);
    hipLaunchKernelGGL(cb_norms3, dim3(40), dim3(256), 0, stream,
                       (const float*)d_in[15], (const float*)d_in[28], (const float*)d_in[41], cbn);
    for (int j = 0; j < 2; ++j)
        hipLaunchKernelGGL(attn_combine, dim3(1), dim3(256), 0, stream,
                           (const float*)d_in[42 + 4 * j], (const float*)d_in[42 + 4 * j + 1],
                           (const float*)d_in[42 + 4 * j + 2], (const float*)d_in[42 + 4 * j + 3],
                           WCH + j * 4096, bcomb + j * 64);

    GemmB g{};
    // ---- encoders (split-bf16, fp32-grade) ----
    for (int l = 0; l < 3; ++l) {
        g.Ah[l] = XH + (size_t)l * BSZ * 512; g.Al[l] = XL + (size_t)l * BSZ * 512;
        g.Wh[l] = ew1h[l]; g.Wl[l] = ew1l[l];
        g.bias[l] = (const float*)d_in[3 + 13 * l + 1];
        g.Ch[l] = H1H + (size_t)l * BSZ * 256; g.Cl[l] = H1L + (size_t)l * BSZ * 256;
    }
    hipLaunchKernelGGL((gemm4<1, 128, 1>), dim3(2, 128, 3), dim3(256), 0, stream, g, BSZ, 256, 512, 1);
    for (int l = 0; l < 3; ++l) {
        g.Ah[l] = H1H + (size_t)l * BSZ * 256; g.Al[l] = H1L + (size_t)l * BSZ * 256;
        g.Wh[l] = ew2h[l]; g.Wl[l] = ew2l[l];
        g.bias[l] = (const float*)d_in[3 + 13 * l + 3];
        g.Ch[l] = H2H + (size_t)l * BSZ * 256; g.Cl[l] = H2L + (size_t)l * BSZ * 256;
    }
    hipLaunchKernelGGL((gemm4<1, 128, 1>), dim3(2, 128, 3), dim3(256), 0, stream, g, BSZ, 256, 256, 1);
    for (int l = 0; l < 3; ++l) {
        g.Ah[l] = H2H + (size_t)l * BSZ * 256; g.Al[l] = H2L + (size_t)l * BSZ * 256;
        g.Wh[l] = ew3h[l]; g.Wl[l] = ew3l[l];
        g.bias[l] = (const float*)d_in[3 + 13 * l + 5];
        g.Ch[l] = ZEH + (size_t)l * BSZ * 64; g.Cl[l] = ZEL + (size_t)l * BSZ * 64;
    }
    hipLaunchKernelGGL((gemm4<1, 64, 1>), dim3(1, 128, 3), dim3(256), 0, stream, g, BSZ, 64, 256, 0);

    // ---- VQ: 10 chunks of 1024 entries ----
    VqB vb;
    {
        int c = 0;
        for (int l = 0; l < 3; ++l) {
            const int nch = CB_SIZES[l] / 1024;
            const int cb_off = (l == 0) ? 0 : (l == 1 ? 2048 : 6144);
            for (int k = 0; k < nch; ++k, ++c) {
                vb.zh[c] = ZEH + (size_t)l * BSZ * 64;
                vb.zl[c] = ZEL + (size_t)l * BSZ * 64;
                vb.ch[c] = cbh[l]; vb.cl[c] = cbl[l];
                vb.nn[c] = cbn + cb_off;
                vb.ebase[c] = k * 1024;
                vb.bkoff[c] = l * BSZ;
            }
        }
    }
    hipLaunchKernelGGL(vq_sweep, dim3(BSZ / 64, 10), dim3(256), 0, stream, vb, bk);
    hipLaunchKernelGGL(gather_b, dim3(3 * BSZ * 64 / 256), dim3(256), 0, stream,
                       bk, cbh[0], cbl[0], cbh[1], cbl[1], cbh[2], cbl[2], ZQH, ZQL);

    // ---- folded attention (loss-only, plain bf16) ----
    for (int j = 0; j < 3; ++j) {
        const int jj = j < 2 ? j : 1;
        g.Ah[j] = ZQH + (size_t)jj * BSZ * 64; g.Al[j] = g.Ah[j];
        g.Wh[j] = WCH + jj * 4096; g.Wl[j] = g.Wh[j];
        g.bias[j] = bcomb + jj * 64;
        g.Cf[j] = ATT + (size_t)jj * BSZ * 64;
    }
    hipLaunchKernelGGL((gemm4<0, 64, 0>), dim3(1, 128, 2), dim3(256), 0, stream, g, BSZ, 64, 64, 0);

    // ---- losses ----
    hipLaunchKernelGGL(loss_b, dim3(256, 1, 3), dim3(256), 0, stream,
                       ZEH, ZEL, ZQH, ZQL, ATT, vq_loss, commit, 1.0f / (float)(BSZ * 64));

    // ---- decoders (plain bf16, hi planes) ----
    for (int l = 0; l < 3; ++l) {
        g.Ah[l] = ZQH + (size_t)l * BSZ * 64; g.Al[l] = g.Ah[l];
        g.Wh[l] = dw1h[l]; g.Wl[l] = g.Wh[l];
        g.bias[l] = (const float*)d_in[3 + 13 * l + 7];
        g.Ch[l] = H1H + (size_t)l * BSZ * 256;
    }
    hipLaunchKernelGGL((gemm4<0, 128, 2>), dim3(2, 128, 3), dim3(256), 0, stream, g, BSZ, 256, 64, 1);
    for (int l = 0; l < 3; ++l) {
        g.Ah[l] = H1H + (size_t)l * BSZ * 256; g.Al[l] = g.Ah[l];
        g.Wh[l] = dw2h[l]; g.Wl[l] = g.Wh[l];
        g.bias[l] = (const float*)d_in[3 + 13 * l + 9];
        g.Ch[l] = H2H + (size_t)l * BSZ * 256;
    }
    hipLaunchKernelGGL((gemm4<0, 128, 2>), dim3(2, 128, 3), dim3(256), 0, stream, g, BSZ, 256, 256, 1);
    for (int l = 0; l < 3; ++l) {
        g.Ah[l] = H2H + (size_t)l * BSZ * 256; g.Al[l] = g.Ah[l];
        g.Wh[l] = dw3h[l]; g.Wl[l] = g.Wh[l];
        g.bias[l] = (const float*)d_in[3 + 13 * l + 11];
        g.Cf[l] = out + (size_t)l * BSZ * 512;
    }
    hipLaunchKernelGGL((gemm4<0, 128, 0>), dim3(4, 128, 3), dim3(256), 0, stream, g, BSZ, 512, 256, 0);
}

// Round 6
// 679.364 us; speedup vs baseline: 1.9951x; 1.9951x over previous
//
#include <hip/hip_runtime.h>

#define BSZ 16384

typedef __attribute__((ext_vector_type(8))) short bf16x8;
typedef __attribute__((ext_vector_type(4))) float f32x4;

__device__ inline unsigned short f2bf(float x) {
    unsigned u = __float_as_uint(x);
    u += 0x7fffu + ((u >> 16) & 1u);
    return (unsigned short)(u >> 16);
}
__device__ inline float bf2f(unsigned short h) {
    return __uint_as_float(((unsigned)h) << 16);
}

// async global->LDS, 16B per lane; l must be wave-uniform base (lane*16 added by HW)
__device__ inline void gld16(const void* g, void* l) {
    __builtin_amdgcn_global_load_lds((const __attribute__((address_space(1))) unsigned*)g,
                                     (__attribute__((address_space(3))) unsigned*)l, 16, 0, 0);
}

// ---------------- prep: fp32 -> separate hi/lo bf16 planes ----------------
struct PrepArgs {
    const float* src[26];
    unsigned short* dsth[26];
    unsigned short* dstl[26];
    int start[26];   // prefix (elements); all sizes multiples of 1024
    int nseg;
};
__global__ __launch_bounds__(256) void prep_kernel(PrepArgs pa) {
    const int base = blockIdx.x << 10;
    int seg = 0;
    #pragma unroll 1
    for (int i = 0; i < 25; ++i)
        if (seg + 1 < pa.nseg && base >= pa.start[seg + 1]) seg++;
    const int off = base - pa.start[seg] + (threadIdx.x << 2);
    const float4 v = *(const float4*)(pa.src[seg] + off);
    ushort4 h, l;
    h.x = f2bf(v.x); h.y = f2bf(v.y); h.z = f2bf(v.z); h.w = f2bf(v.w);
    l.x = f2bf(v.x - bf2f(h.x)); l.y = f2bf(v.y - bf2f(h.y));
    l.z = f2bf(v.z - bf2f(h.z)); l.w = f2bf(v.w - bf2f(h.w));
    *(ushort4*)(pa.dsth[seg] + off) = h;
    *(ushort4*)(pa.dstl[seg] + off) = l;
}

// ---------------- codebook norms (all 3 levels, fp32 inputs) ----------------
__global__ __launch_bounds__(256) void cb_norms3(
    const float* __restrict__ c0, const float* __restrict__ c1,
    const float* __restrict__ c2, float* __restrict__ cbn)
{
    const int r = blockIdx.x * 256 + threadIdx.x;   // 0..10239
    const float* src; int off;
    if (r < 2048) { src = c0; off = r; }
    else if (r < 6144) { src = c1; off = r - 2048; }
    else { src = c2; off = r - 6144; }
    const float4* p = (const float4*)(src + (size_t)off * 64);
    float s = 0.f;
    #pragma unroll
    for (int c = 0; c < 16; ++c) {
        float4 v = p[c];
        s += v.x * v.x + v.y * v.y + v.z * v.z + v.w * v.w;
    }
    cbn[r] = s;
}

// ---------------- attention fold: W_comb = ow@wv (hi plane), b_comb = ow@bv + ob ----
__global__ __launch_bounds__(256) void attn_combine(
    const float* __restrict__ iw, const float* __restrict__ ib,
    const float* __restrict__ ow, const float* __restrict__ ob,
    unsigned short* __restrict__ wch, float* __restrict__ bcomb)
{
    __shared__ float o[4096], v[4096];
    const float* wv = iw + 128 * 64;
    for (int t = threadIdx.x; t < 4096; t += 256) { o[t] = ow[t]; v[t] = wv[t]; }
    __syncthreads();
    for (int t = threadIdx.x; t < 4096; t += 256) {
        const int j = t >> 6, i = t & 63;
        float s = 0.f;
        #pragma unroll
        for (int k = 0; k < 64; ++k) s += o[j * 64 + k] * v[k * 64 + i];
        wch[t] = f2bf(s);
    }
    if (threadIdx.x < 64) {
        const int j = threadIdx.x;
        const float* bv = ib + 128;
        float s = ob[j];
        #pragma unroll
        for (int k = 0; k < 64; ++k) s += o[j * 64 + k] * bv[k];
        bcomb[j] = s;
    }
}

// ---------------- batched MFMA GEMM, m97-style staging, separate planes ----------
// Per z: C = act(A @ W^T + bias). BM=128, BK=32, BN in {64,128}.
// OUT: 0 = f32, 1 = hi+lo planes, 2 = hi plane only.
struct GemmB {
    const unsigned short* Ah[3]; const unsigned short* Al[3];
    const unsigned short* Wh[3]; const unsigned short* Wl[3];
    const float* bias[3];
    float* Cf[3]; unsigned short* Ch[3]; unsigned short* Cl[3];
};
template<int SPLIT, int BN, int OUT>
__global__ __launch_bounds__(256) void gemm4(GemmB g, int M, int N, int K, int relu)
{
    constexpr int MT = (BN == 128) ? 4 : 2;
    constexpr int ASZ = 128 * 32, WSZ = BN * 32;
    __shared__ __align__(16) unsigned short lds[(1 + SPLIT) * (ASZ + WSZ)];
    unsigned short* sAh = lds;
    unsigned short* sAl = lds + ASZ;                  // SPLIT only
    unsigned short* sWh = lds + (1 + SPLIT) * ASZ;
    unsigned short* sWl = sWh + WSZ;                  // SPLIT only
    const int z = blockIdx.z;
    const unsigned short* Ah = g.Ah[z]; const unsigned short* Al = g.Al[z];
    const unsigned short* Wh = g.Wh[z]; const unsigned short* Wl = g.Wl[z];
    const float* bias = g.bias[z];
    const int tid = threadIdx.x, lane = tid & 63, wv = tid >> 6;
    const int q = lane >> 4, c16 = lane & 15;
    const int m0 = blockIdx.y << 7, n0 = blockIdx.x * BN;
    const int wm = (BN == 128) ? (wv >> 1) : wv;
    const int wn = (BN == 128) ? (wv & 1) : 0;
    const int wbase = tid & 192;

    f32x4 acc[MT][4] = {};

    for (int k0 = 0; k0 < K; k0 += 32) {
        __syncthreads();
        #pragma unroll
        for (int i = 0; i < 2; ++i) {      // A: 512 16B-chunks
            const int ch = (i << 8) + tid;
            const int row = ch >> 2, col = (ch & 3) << 3;
            const size_t gofs = (size_t)(m0 + row) * K + k0 + col;
            const int lofs = ((i << 8) + wbase) << 3;
            gld16(Ah + gofs, sAh + lofs);
            if (SPLIT) gld16(Al + gofs, sAl + lofs);
        }
        #pragma unroll
        for (int i = 0; i < BN / 64; ++i) { // W: BN*4 16B-chunks
            const int ch = (i << 8) + tid;
            const int row = ch >> 2, col = (ch & 3) << 3;
            const size_t gofs = (size_t)(n0 + row) * K + k0 + col;
            const int lofs = ((i << 8) + wbase) << 3;
            gld16(Wh + gofs, sWh + lofs);
            if (SPLIT) gld16(Wl + gofs, sWl + lofs);
        }
        __syncthreads();

        bf16x8 fah[MT], fal[MT], fbh[4], fbl[4];
        #pragma unroll
        for (int mt = 0; mt < MT; ++mt) {
            const int r = (BN == 128 ? wm * 64 : wv * 32) + mt * 16 + c16;
            fah[mt] = *(const bf16x8*)&sAh[r * 32 + q * 8];
            if (SPLIT) fal[mt] = *(const bf16x8*)&sAl[r * 32 + q * 8];
        }
        #pragma unroll
        for (int nt = 0; nt < 4; ++nt) {
            const int r = wn * 64 + nt * 16 + c16;
            fbh[nt] = *(const bf16x8*)&sWh[r * 32 + q * 8];
            if (SPLIT) fbl[nt] = *(const bf16x8*)&sWl[r * 32 + q * 8];
        }
        #pragma unroll
        for (int nt = 0; nt < 4; ++nt)
            #pragma unroll
            for (int mt = 0; mt < MT; ++mt) {
                acc[mt][nt] = __builtin_amdgcn_mfma_f32_16x16x32_bf16(fah[mt], fbh[nt], acc[mt][nt], 0, 0, 0);
                if (SPLIT) {
                    acc[mt][nt] = __builtin_amdgcn_mfma_f32_16x16x32_bf16(fah[mt], fbl[nt], acc[mt][nt], 0, 0, 0);
                    acc[mt][nt] = __builtin_amdgcn_mfma_f32_16x16x32_bf16(fal[mt], fbh[nt], acc[mt][nt], 0, 0, 0);
                }
            }
    }

    // epilogue: C/D layout col=lane&15, row=(lane>>4)*4+reg
    #pragma unroll
    for (int nt = 0; nt < 4; ++nt) {
        const int gcol = n0 + wn * 64 + nt * 16 + c16;
        const float bb = bias[gcol];
        #pragma unroll
        for (int mt = 0; mt < MT; ++mt)
            #pragma unroll
            for (int r = 0; r < 4; ++r) {
                const int grow = m0 + (BN == 128 ? wm * 64 : wv * 32) + mt * 16 + q * 4 + r;
                float v = acc[mt][nt][r] + bb;
                if (relu) v = fmaxf(v, 0.f);
                const size_t o = (size_t)grow * N + gcol;
                if (OUT == 0) g.Cf[z][o] = v;
                else {
                    const unsigned short h = f2bf(v);
                    g.Ch[z][o] = h;
                    if (OUT == 1) g.Cl[z][o] = f2bf(v - bf2f(h));
                }
            }
    }
}

// ---------------- VQ sweep: split-bf16 MFMA distances ----------------
// grid (256, 10): 64 samples x 1024-entry chunk. Double-buffered cb tiles with
// STATIC slot indices (2x manual unroll). Float dist + int idx select in-loop;
// cross-block merge via atomicMin on (monotonic-mapped dist | idx) u64 keys.
struct VqB {
    const unsigned short* zh[10]; const unsigned short* zl[10];
    const unsigned short* ch[10]; const unsigned short* cl[10];
    const float* nn[10];
    int ebase[10]; int bkoff[10];
};
__global__ __launch_bounds__(256) void vq_sweep(VqB vb, unsigned long long* __restrict__ bk)
{
    __shared__ float bds[64][4];
    __shared__ int   bis[64][4];
    const int tid = threadIdx.x, lane = tid & 63, wv = tid >> 6;
    const int q = lane >> 4, c16 = lane & 15;
    const int ck = blockIdx.y;
    const size_t s0 = (size_t)blockIdx.x << 6;
    const unsigned short* zh = vb.zh[ck]; const unsigned short* zl = vb.zl[ck];
    const unsigned short* ch = vb.ch[ck]; const unsigned short* cl = vb.cl[ck];
    const float* nn = vb.nn[ck];
    const int eb = vb.ebase[ck];

    // A frags (z) in registers for the whole sweep (direct b128 plane loads)
    bf16x8 ah[4][2], al[4][2];
    #pragma unroll
    for (int mt = 0; mt < 4; ++mt)
        #pragma unroll
        for (int ks = 0; ks < 2; ++ks) {
            const size_t a = ((s0 + mt * 16 + c16) << 6) + (ks << 5) + (q << 3);
            ah[mt][ks] = *(const bf16x8*)(zh + a);
            al[mt][ks] = *(const bf16x8*)(zl + a);
        }

    float bd[4][4];
    int   bi[4][4];
    #pragma unroll
    for (int mt = 0; mt < 4; ++mt)
        #pragma unroll
        for (int r = 0; r < 4; ++r) { bd[mt][r] = 3.4e38f; bi[mt][r] = 0x7fffffff; }

    // double-buffered codebook tiles, STATIC slots only
    bf16x8 bh0[2], bl0[2], bh1[2], bl1[2];
    float nn0, nn1;
    auto ld0 = [&](int t) {
        const int e = eb + t * 16 + c16;
        const size_t a = ((size_t)e << 6) + (q << 3);
        bh0[0] = *(const bf16x8*)(ch + a);      bh0[1] = *(const bf16x8*)(ch + a + 32);
        bl0[0] = *(const bf16x8*)(cl + a);      bl0[1] = *(const bf16x8*)(cl + a + 32);
        nn0 = nn[e];
    };
    auto ld1 = [&](int t) {
        const int e = eb + t * 16 + c16;
        const size_t a = ((size_t)e << 6) + (q << 3);
        bh1[0] = *(const bf16x8*)(ch + a);      bh1[1] = *(const bf16x8*)(ch + a + 32);
        bl1[0] = *(const bf16x8*)(cl + a);      bl1[1] = *(const bf16x8*)(cl + a + 32);
        nn1 = nn[e];
    };
    ld0(wv);
    ld1(wv + 4);

    #pragma unroll 1
    for (int ii = 0; ii < 8; ++ii) {
        // ---- slot 0: tile t0 = wv + 8*ii ----
        {
            const int t0 = wv + 8 * ii;
            f32x4 acc[4] = {};
            #pragma unroll
            for (int ks = 0; ks < 2; ++ks)
                #pragma unroll
                for (int mt = 0; mt < 4; ++mt) {
                    acc[mt] = __builtin_amdgcn_mfma_f32_16x16x32_bf16(ah[mt][ks], bh0[ks], acc[mt], 0, 0, 0);
                    acc[mt] = __builtin_amdgcn_mfma_f32_16x16x32_bf16(ah[mt][ks], bl0[ks], acc[mt], 0, 0, 0);
                    acc[mt] = __builtin_amdgcn_mfma_f32_16x16x32_bf16(al[mt][ks], bh0[ks], acc[mt], 0, 0, 0);
                }
            const float nnc = nn0;
            const int idxlo = eb + t0 * 16 + c16;
            if (ii < 7) ld0(t0 + 8);
            #pragma unroll
            for (int mt = 0; mt < 4; ++mt)
                #pragma unroll
                for (int r = 0; r < 4; ++r) {
                    const float dist = fmaf(-2.0f, acc[mt][r], nnc);
                    if (dist < bd[mt][r]) { bd[mt][r] = dist; bi[mt][r] = idxlo; }
                }
        }
        // ---- slot 1: tile t1 = wv + 8*ii + 4 ----
        {
            const int t1 = wv + 8 * ii + 4;
            f32x4 acc[4] = {};
            #pragma unroll
            for (int ks = 0; ks < 2; ++ks)
                #pragma unroll
                for (int mt = 0; mt < 4; ++mt) {
                    acc[mt] = __builtin_amdgcn_mfma_f32_16x16x32_bf16(ah[mt][ks], bh1[ks], acc[mt], 0, 0, 0);
                    acc[mt] = __builtin_amdgcn_mfma_f32_16x16x32_bf16(ah[mt][ks], bl1[ks], acc[mt], 0, 0, 0);
                    acc[mt] = __builtin_amdgcn_mfma_f32_16x16x32_bf16(al[mt][ks], bh1[ks], acc[mt], 0, 0, 0);
                }
            const float nnc = nn1;
            const int idxlo = eb + t1 * 16 + c16;
            if (ii < 7) ld1(t1 + 8);
            #pragma unroll
            for (int mt = 0; mt < 4; ++mt)
                #pragma unroll
                for (int r = 0; r < 4; ++r) {
                    const float dist = fmaf(-2.0f, acc[mt][r], nnc);
                    if (dist < bd[mt][r]) { bd[mt][r] = dist; bi[mt][r] = idxlo; }
                }
        }
    }

    // reduce over the 16 entry-lanes (xor masks < 16 stay within sample group)
    #pragma unroll
    for (int off = 1; off < 16; off <<= 1)
        #pragma unroll
        for (int mt = 0; mt < 4; ++mt)
            #pragma unroll
            for (int r = 0; r < 4; ++r) {
                const float od = __shfl_xor(bd[mt][r], off, 64);
                const int   oi = __shfl_xor(bi[mt][r], off, 64);
                if (od < bd[mt][r] || (od == bd[mt][r] && oi < bi[mt][r])) {
                    bd[mt][r] = od; bi[mt][r] = oi;
                }
            }
    if (c16 == 0)
        #pragma unroll
        for (int mt = 0; mt < 4; ++mt)
            #pragma unroll
            for (int r = 0; r < 4; ++r) {
                const int row = mt * 16 + q * 4 + r;
                bds[row][wv] = bd[mt][r];
                bis[row][wv] = bi[mt][r];
            }
    __syncthreads();
    if (tid < 64) {
        float best = bds[tid][0];
        int   bidx = bis[tid][0];
        #pragma unroll
        for (int w2 = 1; w2 < 4; ++w2) {
            const float d = bds[tid][w2];
            const int   i2 = bis[tid][w2];
            if (d < best || (d == best && i2 < bidx)) { best = d; bidx = i2; }
        }
        // monotonic float->u32 map (handles negative dists), then (dist,idx) u64 key
        const unsigned f = __float_as_uint(best);
        const unsigned m = (f & 0x80000000u) ? ~f : (f | 0x80000000u);
        const unsigned long long key = ((unsigned long long)m << 32) | (unsigned)bidx;
        atomicMin(&bk[vb.bkoff[ck] + s0 + tid], key);
    }
}

// ---------------- gather zq planes from final keys ----------------
__global__ __launch_bounds__(256) void gather_b(
    const unsigned long long* __restrict__ bk,
    const unsigned short* __restrict__ ch0, const unsigned short* __restrict__ cl0,
    const unsigned short* __restrict__ ch1, const unsigned short* __restrict__ cl1,
    const unsigned short* __restrict__ ch2, const unsigned short* __restrict__ cl2,
    unsigned short* __restrict__ zqh, unsigned short* __restrict__ zql)
{
    const int gid = blockIdx.x * 256 + threadIdx.x;   // 0 .. 3*B*64
    const int l = gid / (BSZ * 64);
    const int r = gid - l * (BSZ * 64);
    const int s = r >> 6, d = r & 63;
    const int idx = (int)(unsigned)(bk[(size_t)l * BSZ + s] & 0xffffffffULL);
    const unsigned short* ch = (l == 0) ? ch0 : (l == 1 ? ch1 : ch2);
    const unsigned short* cl = (l == 0) ? cl0 : (l == 1 ? cl1 : cl2);
    zqh[gid] = ch[(size_t)idx * 64 + d];
    zql[gid] = cl[(size_t)idx * 64 + d];
}

// ---------------- batched losses ----------------
__global__ __launch_bounds__(256) void loss_b(
    const unsigned short* __restrict__ zeh, const unsigned short* __restrict__ zel,
    const unsigned short* __restrict__ zqh, const unsigned short* __restrict__ zql,
    const float* __restrict__ attb, float* __restrict__ vq_out,
    float* __restrict__ commit_out, float inv)
{
    const int l = blockIdx.z;
    const size_t base = (size_t)l * BSZ * 64;
    const float* at = (l > 0) ? attb + (size_t)(l - 1) * BSZ * 64 : nullptr;
    float cs = 0.f, vs = 0.f;
    for (int t = blockIdx.x * 256 + threadIdx.x; t < BSZ * 64; t += gridDim.x * 256) {
        const float e = bf2f(zeh[base + t]) + bf2f(zel[base + t]);
        const float qv = bf2f(zqh[base + t]) + bf2f(zql[base + t]);
        const float dc = e - qv;
        cs += dc * dc;
        const float za = at ? (e + at[t]) : e;
        const float dv = qv - za;
        vs += dv * dv;
    }
    #pragma unroll
    for (int off = 32; off; off >>= 1) {
        cs += __shfl_down(cs, off, 64);
        vs += __shfl_down(vs, off, 64);
    }
    __shared__ float sc[4], sv[4];
    const int lane = threadIdx.x & 63, w = threadIdx.x >> 6;
    if (lane == 0) { sc[w] = cs; sv[w] = vs; }
    __syncthreads();
    if (threadIdx.x == 0) {
        atomicAdd(commit_out, (sc[0] + sc[1] + sc[2] + sc[3]) * inv);
        atomicAdd(vq_out, (sv[0] + sv[1] + sv[2] + sv[3]) * inv);
    }
}

extern "C" void kernel_launch(void* const* d_in, const int* in_sizes, int n_in,
                              void* d_out, int out_size, void* d_ws, size_t ws_size,
                              hipStream_t stream)
{
    const int CB_SIZES[3] = {2048, 4096, 4096};

    // ---- workspace carve-up (256B-aligned segments) ----
    char* wsp = (char*)d_ws;
    auto alloc = [&](size_t bytes) -> void* {
        void* p = wsp; wsp += (bytes + 255) & ~(size_t)255; return p;
    };
    unsigned long long* bk = (unsigned long long*)alloc((size_t)3 * BSZ * 8);
    float* ATT   = (float*)alloc((size_t)2 * BSZ * 64 * 4);
    float* cbn   = (float*)alloc(10240 * 4);
    float* bcomb = (float*)alloc(128 * 4);
    auto u16a = [&](size_t n) -> unsigned short* { return (unsigned short*)alloc(n * 2); };
    unsigned short* XH  = u16a((size_t)3 * BSZ * 512);
    unsigned short* XL  = u16a((size_t)3 * BSZ * 512);
    unsigned short* H1H = u16a((size_t)3 * BSZ * 256);
    unsigned short* H1L = u16a((size_t)3 * BSZ * 256);
    unsigned short* H2H = u16a((size_t)3 * BSZ * 256);
    unsigned short* H2L = u16a((size_t)3 * BSZ * 256);
    unsigned short* ZEH = u16a((size_t)3 * BSZ * 64);
    unsigned short* ZEL = u16a((size_t)3 * BSZ * 64);
    unsigned short* ZQH = u16a((size_t)3 * BSZ * 64);
    unsigned short* ZQL = u16a((size_t)3 * BSZ * 64);
    unsigned short* WCH = u16a(2 * 4096);
    unsigned short* WREG = u16a((size_t)2 * (3 * 425984 + 655360));

    float* out = (float*)d_out;
    float* vq_loss = out + (size_t)3 * BSZ * 512;
    float* commit  = vq_loss + 1;
    hipMemsetAsync(vq_loss, 0, 2 * sizeof(float), stream);
    hipMemsetAsync(bk, 0xFF, (size_t)3 * BSZ * 8, stream);

    // ---- prep descriptor table (x inputs + weights + codebooks) ----
    PrepArgs pa; int pos = 0, ns = 0;
    const unsigned short *ew1h[3], *ew1l[3], *ew2h[3], *ew2l[3], *ew3h[3], *ew3l[3];
    const unsigned short *dw1h[3], *dw1l[3], *dw2h[3], *dw2l[3], *dw3h[3], *dw3l[3];
    const unsigned short *cbh[3], *cbl[3];
    auto add = [&](const float* src, unsigned short* dh, unsigned short* dl, int n) {
        pa.src[ns] = src; pa.dsth[ns] = dh; pa.dstl[ns] = dl; pa.start[ns] = pos;
        pos += n; ns++;
    };
    for (int l = 0; l < 3; ++l)
        add((const float*)d_in[l], XH + (size_t)l * BSZ * 512, XL + (size_t)l * BSZ * 512, BSZ * 512);
    {
        unsigned short* wc = WREG;
        auto addw = [&](const float* src, int n, const unsigned short** ph, const unsigned short** pl) {
            add(src, wc, wc + n, n);
            *ph = wc; *pl = wc + n; wc += 2 * n;
        };
        for (int l = 0; l < 3; ++l) {
            const int base = 3 + 13 * l;
            addw((const float*)d_in[base + 0], 256 * 512, &ew1h[l], &ew1l[l]);
            addw((const float*)d_in[base + 2], 256 * 256, &ew2h[l], &ew2l[l]);
            addw((const float*)d_in[base + 4], 64 * 256,  &ew3h[l], &ew3l[l]);
            addw((const float*)d_in[base + 6], 256 * 64,  &dw1h[l], &dw1l[l]);
            addw((const float*)d_in[base + 8], 256 * 256, &dw2h[l], &dw2l[l]);
            addw((const float*)d_in[base + 10], 512 * 256, &dw3h[l], &dw3l[l]);
            addw((const float*)d_in[base + 12], CB_SIZES[l] * 64, &cbh[l], &cbl[l]);
        }
    }
    pa.nseg = ns;
    for (int i = ns; i < 26; ++i) pa.start[i] = 0x7fffffff;

    hipLaunchKernelGGL(prep_kernel, dim3(pos >> 10), dim3(256), 0, stream, pa);
    hipLaunchKernelGGL(cb_norms3, dim3(40), dim3(256), 0, stream,
                       (const float*)d_in[15], (const float*)d_in[28], (const float*)d_in[41], cbn);
    for (int j = 0; j < 2; ++j)
        hipLaunchKernelGGL(attn_combine, dim3(1), dim3(256), 0, stream,
                           (const float*)d_in[42 + 4 * j], (const float*)d_in[42 + 4 * j + 1],
                           (const float*)d_in[42 + 4 * j + 2], (const float*)d_in[42 + 4 * j + 3],
                           WCH + j * 4096, bcomb + j * 64);

    GemmB g{};
    // ---- encoders (split-bf16, fp32-grade) ----
    for (int l = 0; l < 3; ++l) {
        g.Ah[l] = XH + (size_t)l * BSZ * 512; g.Al[l] = XL + (size_t)l * BSZ * 512;
        g.Wh[l] = ew1h[l]; g.Wl[l] = ew1l[l];
        g.bias[l] = (const float*)d_in[3 + 13 * l + 1];
        g.Ch[l] = H1H + (size_t)l * BSZ * 256; g.Cl[l] = H1L + (size_t)l * BSZ * 256;
    }
    hipLaunchKernelGGL((gemm4<1, 128, 1>), dim3(2, 128, 3), dim3(256), 0, stream, g, BSZ, 256, 512, 1);
    for (int l = 0; l < 3; ++l) {
        g.Ah[l] = H1H + (size_t)l * BSZ * 256; g.Al[l] = H1L + (size_t)l * BSZ * 256;
        g.Wh[l] = ew2h[l]; g.Wl[l] = ew2l[l];
        g.bias[l] = (const float*)d_in[3 + 13 * l + 3];
        g.Ch[l] = H2H + (size_t)l * BSZ * 256; g.Cl[l] = H2L + (size_t)l * BSZ * 256;
    }
    hipLaunchKernelGGL((gemm4<1, 128, 1>), dim3(2, 128, 3), dim3(256), 0, stream, g, BSZ, 256, 256, 1);
    for (int l = 0; l < 3; ++l) {
        g.Ah[l] = H2H + (size_t)l * BSZ * 256; g.Al[l] = H2L + (size_t)l * BSZ * 256;
        g.Wh[l] = ew3h[l]; g.Wl[l] = ew3l[l];
        g.bias[l] = (const float*)d_in[3 + 13 * l + 5];
        g.Ch[l] = ZEH + (size_t)l * BSZ * 64; g.Cl[l] = ZEL + (size_t)l * BSZ * 64;
    }
    hipLaunchKernelGGL((gemm4<1, 64, 1>), dim3(1, 128, 3), dim3(256), 0, stream, g, BSZ, 64, 256, 0);

    // ---- VQ: 10 chunks of 1024 entries ----
    VqB vb;
    {
        int c = 0;
        for (int l = 0; l < 3; ++l) {
            const int nch = CB_SIZES[l] / 1024;
            const int cb_off = (l == 0) ? 0 : (l == 1 ? 2048 : 6144);
            for (int k = 0; k < nch; ++k, ++c) {
                vb.zh[c] = ZEH + (size_t)l * BSZ * 64;
                vb.zl[c] = ZEL + (size_t)l * BSZ * 64;
                vb.ch[c] = cbh[l]; vb.cl[c] = cbl[l];
                vb.nn[c] = cbn + cb_off;
                vb.ebase[c] = k * 1024;
                vb.bkoff[c] = l * BSZ;
            }
        }
    }
    hipLaunchKernelGGL(vq_sweep, dim3(BSZ / 64, 10), dim3(256), 0, stream, vb, bk);
    hipLaunchKernelGGL(gather_b, dim3(3 * BSZ * 64 / 256), dim3(256), 0, stream,
                       bk, cbh[0], cbl[0], cbh[1], cbl[1], cbh[2], cbl[2], ZQH, ZQL);

    // ---- folded attention (loss-only, plain bf16) ----
    for (int j = 0; j < 3; ++j) {
        const int jj = j < 2 ? j : 1;
        g.Ah[j] = ZQH + (size_t)jj * BSZ * 64; g.Al[j] = g.Ah[j];
        g.Wh[j] = WCH + jj * 4096; g.Wl[j] = g.Wh[j];
        g.bias[j] = bcomb + jj * 64;
        g.Cf[j] = ATT + (size_t)jj * BSZ * 64;
    }
    hipLaunchKernelGGL((gemm4<0, 64, 0>), dim3(1, 128, 2), dim3(256), 0, stream, g, BSZ, 64, 64, 0);

    // ---- losses ----
    hipLaunchKernelGGL(loss_b, dim3(256, 1, 3), dim3(256), 0, stream,
                       ZEH, ZEL, ZQH, ZQL, ATT, vq_loss, commit, 1.0f / (float)(BSZ * 64));

    // ---- decoders (plain bf16, hi planes) ----
    for (int l = 0; l < 3; ++l) {
        g.Ah[l] = ZQH + (size_t)l * BSZ * 64; g.Al[l] = g.Ah[l];
        g.Wh[l] = dw1h[l]; g.Wl[l] = g.Wh[l];
        g.bias[l] = (const float*)d_in[3 + 13 * l + 7];
        g.Ch[l] = H1H + (size_t)l * BSZ * 256;
    }
    hipLaunchKernelGGL((gemm4<0, 128, 2>), dim3(2, 128, 3), dim3(256), 0, stream, g, BSZ, 256, 64, 1);
    for (int l = 0; l < 3; ++l) {
        g.Ah[l] = H1H + (size_t)l * BSZ * 256; g.Al[l] = g.Ah[l];
        g.Wh[l] = dw2h[l]; g.Wl[l] = g.Wh[l];
        g.bias[l] = (const float*)d_in[3 + 13 * l + 9];
        g.Ch[l] = H2H + (size_t)l * BSZ * 256;
    }
    hipLaunchKernelGGL((gemm4<0, 128, 2>), dim3(2, 128, 3), dim3(256), 0, stream, g, BSZ, 256, 256, 1);
    for (int l = 0; l < 3; ++l) {
        g.Ah[l] = H2H + (size_t)l * BSZ * 256; g.Al[l] = g.Ah[l];
        g.Wh[l] = dw3h[l]; g.Wl[l] = g.Wh[l];
        g.bias[l] = (const float*)d_in[3 + 13 * l + 11];
        g.Cf[l] = out + (size_t)l * BSZ * 512;
    }
    hipLaunchKernelGGL((gemm4<0, 128, 0>), dim3(4, 128, 3), dim3(256), 0, stream, g, BSZ, 512, 256, 0);
}

// Round 7
// 649.091 us; speedup vs baseline: 2.0881x; 1.0466x over previous
//
#include <hip/hip_runtime.h>

#define BSZ 16384

typedef __attribute__((ext_vector_type(8))) short bf16x8;
typedef __attribute__((ext_vector_type(4))) float f32x4;

__device__ inline unsigned short f2bf(float x) {
    unsigned u = __float_as_uint(x);
    u += 0x7fffu + ((u >> 16) & 1u);
    return (unsigned short)(u >> 16);
}
__device__ inline float bf2f(unsigned short h) {
    return __uint_as_float(((unsigned)h) << 16);
}

// async global->LDS, 16B per lane; lds dst must be wave-uniform base (+lane*16 by HW)
__device__ inline void gld16(const void* g, void* l) {
    __builtin_amdgcn_global_load_lds((const __attribute__((address_space(1))) unsigned*)g,
                                     (__attribute__((address_space(3))) unsigned*)l, 16, 0, 0);
}

// ---------------- prep: fp32 -> separate hi/lo bf16 planes ----------------
struct PrepArgs {
    const float* src[26];
    unsigned short* dsth[26];
    unsigned short* dstl[26];
    int start[26];   // prefix (elements); all sizes multiples of 1024
    int nseg;
};
__global__ __launch_bounds__(256) void prep_kernel(PrepArgs pa) {
    const int base = blockIdx.x << 10;
    int seg = 0;
    #pragma unroll 1
    for (int i = 0; i < 25; ++i)
        if (seg + 1 < pa.nseg && base >= pa.start[seg + 1]) seg++;
    const int off = base - pa.start[seg] + (threadIdx.x << 2);
    const float4 v = *(const float4*)(pa.src[seg] + off);
    ushort4 h, l;
    h.x = f2bf(v.x); h.y = f2bf(v.y); h.z = f2bf(v.z); h.w = f2bf(v.w);
    l.x = f2bf(v.x - bf2f(h.x)); l.y = f2bf(v.y - bf2f(h.y));
    l.z = f2bf(v.z - bf2f(h.z)); l.w = f2bf(v.w - bf2f(h.w));
    *(ushort4*)(pa.dsth[seg] + off) = h;
    *(ushort4*)(pa.dstl[seg] + off) = l;
}

// ---------------- codebook norms (all 3 levels, fp32 inputs) ----------------
__global__ __launch_bounds__(256) void cb_norms3(
    const float* __restrict__ c0, const float* __restrict__ c1,
    const float* __restrict__ c2, float* __restrict__ cbn)
{
    const int r = blockIdx.x * 256 + threadIdx.x;   // 0..10239
    const float* src; int off;
    if (r < 2048) { src = c0; off = r; }
    else if (r < 6144) { src = c1; off = r - 2048; }
    else { src = c2; off = r - 6144; }
    const float4* p = (const float4*)(src + (size_t)off * 64);
    float s = 0.f;
    #pragma unroll
    for (int c = 0; c < 16; ++c) {
        float4 v = p[c];
        s += v.x * v.x + v.y * v.y + v.z * v.z + v.w * v.w;
    }
    cbn[r] = s;
}

// ---------------- attention fold (both heads): W_comb = ow@wv, b_comb = ow@bv + ob --
struct AttnA {
    const float* iw[2]; const float* ib[2];
    const float* ow[2]; const float* ob[2];
    unsigned short* wch[2]; float* bc[2];
};
__global__ __launch_bounds__(256) void attn_combine(AttnA a) {
    const int j = blockIdx.x;
    __shared__ float o[4096], v[4096];
    const float* wv = a.iw[j] + 128 * 64;
    for (int t = threadIdx.x; t < 4096; t += 256) { o[t] = a.ow[j][t]; v[t] = wv[t]; }
    __syncthreads();
    for (int t = threadIdx.x; t < 4096; t += 256) {
        const int r = t >> 6, i = t & 63;
        float s = 0.f;
        #pragma unroll
        for (int k = 0; k < 64; ++k) s += o[r * 64 + k] * v[k * 64 + i];
        a.wch[j][t] = f2bf(s);
    }
    if (threadIdx.x < 64) {
        const int r = threadIdx.x;
        const float* bv = a.ib[j] + 128;
        float s = a.ob[j][r];
        #pragma unroll
        for (int k = 0; k < 64; ++k) s += o[r * 64 + k] * bv[k];
        a.bc[j][r] = s;
    }
}

// ---------------- batched MFMA GEMM, m97-style staging, separate planes ----------
// Per z: C = act(A @ W^T + bias). BM=128, BK=32, BN in {64,128}.
// OUT: 0 = f32, 1 = hi+lo planes, 2 = hi plane only.
struct GemmB {
    const unsigned short* Ah[3]; const unsigned short* Al[3];
    const unsigned short* Wh[3]; const unsigned short* Wl[3];
    const float* bias[3];
    float* Cf[3]; unsigned short* Ch[3]; unsigned short* Cl[3];
};
template<int SPLIT, int BN, int OUT>
__global__ __launch_bounds__(256) void gemm4(GemmB g, int M, int N, int K, int relu)
{
    constexpr int MT = (BN == 128) ? 4 : 2;
    constexpr int ASZ = 128 * 32, WSZ = BN * 32;
    __shared__ __align__(16) unsigned short lds[(1 + SPLIT) * (ASZ + WSZ)];
    unsigned short* sAh = lds;
    unsigned short* sAl = lds + ASZ;                  // SPLIT only
    unsigned short* sWh = lds + (1 + SPLIT) * ASZ;
    unsigned short* sWl = sWh + WSZ;                  // SPLIT only
    const int z = blockIdx.z;
    const unsigned short* Ah = g.Ah[z]; const unsigned short* Al = g.Al[z];
    const unsigned short* Wh = g.Wh[z]; const unsigned short* Wl = g.Wl[z];
    const float* bias = g.bias[z];
    const int tid = threadIdx.x, lane = tid & 63, wv = tid >> 6;
    const int q = lane >> 4, c16 = lane & 15;
    const int m0 = blockIdx.y << 7, n0 = blockIdx.x * BN;
    const int wm = (BN == 128) ? (wv >> 1) : wv;
    const int wn = (BN == 128) ? (wv & 1) : 0;
    const int wbase = tid & 192;

    f32x4 acc[MT][4] = {};

    for (int k0 = 0; k0 < K; k0 += 32) {
        __syncthreads();
        #pragma unroll
        for (int i = 0; i < 2; ++i) {      // A: 512 16B-chunks
            const int ch = (i << 8) + tid;
            const int row = ch >> 2, col = (ch & 3) << 3;
            const size_t gofs = (size_t)(m0 + row) * K + k0 + col;
            const int lofs = ((i << 8) + wbase) << 3;
            gld16(Ah + gofs, sAh + lofs);
            if (SPLIT) gld16(Al + gofs, sAl + lofs);
        }
        #pragma unroll
        for (int i = 0; i < BN / 64; ++i) { // W: BN*4 16B-chunks
            const int ch = (i << 8) + tid;
            const int row = ch >> 2, col = (ch & 3) << 3;
            const size_t gofs = (size_t)(n0 + row) * K + k0 + col;
            const int lofs = ((i << 8) + wbase) << 3;
            gld16(Wh + gofs, sWh + lofs);
            if (SPLIT) gld16(Wl + gofs, sWl + lofs);
        }
        __syncthreads();

        bf16x8 fah[MT], fal[MT], fbh[4], fbl[4];
        #pragma unroll
        for (int mt = 0; mt < MT; ++mt) {
            const int r = (BN == 128 ? wm * 64 : wv * 32) + mt * 16 + c16;
            fah[mt] = *(const bf16x8*)&sAh[r * 32 + q * 8];
            if (SPLIT) fal[mt] = *(const bf16x8*)&sAl[r * 32 + q * 8];
        }
        #pragma unroll
        for (int nt = 0; nt < 4; ++nt) {
            const int r = wn * 64 + nt * 16 + c16;
            fbh[nt] = *(const bf16x8*)&sWh[r * 32 + q * 8];
            if (SPLIT) fbl[nt] = *(const bf16x8*)&sWl[r * 32 + q * 8];
        }
        #pragma unroll
        for (int nt = 0; nt < 4; ++nt)
            #pragma unroll
            for (int mt = 0; mt < MT; ++mt) {
                acc[mt][nt] = __builtin_amdgcn_mfma_f32_16x16x32_bf16(fah[mt], fbh[nt], acc[mt][nt], 0, 0, 0);
                if (SPLIT) {
                    acc[mt][nt] = __builtin_amdgcn_mfma_f32_16x16x32_bf16(fah[mt], fbl[nt], acc[mt][nt], 0, 0, 0);
                    acc[mt][nt] = __builtin_amdgcn_mfma_f32_16x16x32_bf16(fal[mt], fbh[nt], acc[mt][nt], 0, 0, 0);
                }
            }
    }

    // epilogue: C/D layout col=lane&15, row=(lane>>4)*4+reg
    #pragma unroll
    for (int nt = 0; nt < 4; ++nt) {
        const int gcol = n0 + wn * 64 + nt * 16 + c16;
        const float bb = bias[gcol];
        #pragma unroll
        for (int mt = 0; mt < MT; ++mt)
            #pragma unroll
            for (int r = 0; r < 4; ++r) {
                const int grow = m0 + (BN == 128 ? wm * 64 : wv * 32) + mt * 16 + q * 4 + r;
                float v = acc[mt][nt][r] + bb;
                if (relu) v = fmaxf(v, 0.f);
                const size_t o = (size_t)grow * N + gcol;
                if (OUT == 0) g.Cf[z][o] = v;
                else {
                    const unsigned short h = f2bf(v);
                    g.Ch[z][o] = h;
                    if (OUT == 1) g.Cl[z][o] = f2bf(v - bf2f(h));
                }
            }
    }
}

// ---------------- VQ sweep: m97-style LDS-staged split-bf16 MFMA distances ----------
// grid (256, 10): 64 samples x 1024-entry chunk. Entries streamed in 64-entry tiles
// through LDS via gld16 (hi+lo, 16 KB/tile) with XOR chunk-swizzle folded into the
// per-lane GLOBAL source offset (LDS dst stays lane-linear as gld16 requires).
// Reader ds_read addresses are per-lane constants. Numerics identical to r4/r6.
struct VqB {
    const unsigned short* zh[10]; const unsigned short* zl[10];
    const unsigned short* ch[10]; const unsigned short* cl[10];
    const float* nn[10];
    int ebase[10]; int bkoff[10];
};
__global__ __launch_bounds__(256) void vq_sweep(VqB vb, unsigned long long* __restrict__ bk)
{
    __shared__ __align__(16) unsigned short sh[4096];   // hi 64x64
    __shared__ __align__(16) unsigned short sl[4096];   // lo 64x64
    __shared__ float bds[64][4];
    __shared__ int   bis[64][4];
    const int tid = threadIdx.x, lane = tid & 63, wv = tid >> 6;
    const int q = lane >> 4, c16 = lane & 15;
    const int ck = blockIdx.y;
    const size_t s0 = (size_t)blockIdx.x << 6;
    const unsigned short* zh = vb.zh[ck]; const unsigned short* zl = vb.zl[ck];
    const unsigned short* ch = vb.ch[ck]; const unsigned short* cl = vb.cl[ck];
    const float* nn = vb.nn[ck];
    const int eb = vb.ebase[ck];

    // A frags (z) in registers for the whole sweep
    bf16x8 ah[4][2], al[4][2];
    #pragma unroll
    for (int mt = 0; mt < 4; ++mt)
        #pragma unroll
        for (int ks = 0; ks < 2; ++ks) {
            const size_t a = ((s0 + mt * 16 + c16) << 6) + (ks << 5) + (q << 3);
            ah[mt][ks] = *(const bf16x8*)(zh + a);
            al[mt][ks] = *(const bf16x8*)(zl + a);
        }

    // staging: per-lane swizzled GLOBAL chunk offsets (elements within a 64x64 tile).
    // LDS chunk c = p*256+tid holds (row=c>>3, jpos=c&7) = logical chunk jl=jpos^(row&7).
    int soff[2];
    #pragma unroll
    for (int p = 0; p < 2; ++p) {
        const int c = (p << 8) + tid;
        const int row = c >> 3, jp = c & 7;
        const int jl = jp ^ (row & 7);
        soff[p] = (row << 6) + (jl << 3);
    }
    const int dst0 = (tid & 192) << 4;            // pass 0 LDS byte base (wave-uniform)
    const int dst1 = (256 + (tid & 192)) << 4;    // pass 1

    // per-lane LDS read byte offsets (constant across tiles)
    const int myrow = (wv << 4) + c16;            // entry row within tile
    int roff[2];
    #pragma unroll
    for (int ks = 0; ks < 2; ++ks) {
        const int jl = (ks << 2) + q;
        roff[ks] = (myrow << 7) + (((jl ^ (myrow & 7)) & 7) << 4);
    }

    float bd[4][4];
    int   bi[4][4];
    #pragma unroll
    for (int mt = 0; mt < 4; ++mt)
        #pragma unroll
        for (int r = 0; r < 4; ++r) { bd[mt][r] = 3.4e38f; bi[mt][r] = 0x7fffffff; }

    #pragma unroll 1
    for (int t = 0; t < 16; ++t) {
        const int e0 = eb + (t << 6);
        const size_t tb = (size_t)e0 << 6;
        __syncthreads();
        gld16(ch + tb + soff[0], (char*)sh + dst0);
        gld16(ch + tb + soff[1], (char*)sh + dst1);
        gld16(cl + tb + soff[0], (char*)sl + dst0);
        gld16(cl + tb + soff[1], (char*)sl + dst1);
        const float nnc = nn[e0 + myrow];
        __syncthreads();

        bf16x8 bh[2], bl[2];
        #pragma unroll
        for (int ks = 0; ks < 2; ++ks) {
            bh[ks] = *(const bf16x8*)((const char*)sh + roff[ks]);
            bl[ks] = *(const bf16x8*)((const char*)sl + roff[ks]);
        }
        f32x4 acc[4] = {};
        #pragma unroll
        for (int ks = 0; ks < 2; ++ks)
            #pragma unroll
            for (int mt = 0; mt < 4; ++mt) {
                acc[mt] = __builtin_amdgcn_mfma_f32_16x16x32_bf16(ah[mt][ks], bh[ks], acc[mt], 0, 0, 0);
                acc[mt] = __builtin_amdgcn_mfma_f32_16x16x32_bf16(ah[mt][ks], bl[ks], acc[mt], 0, 0, 0);
                acc[mt] = __builtin_amdgcn_mfma_f32_16x16x32_bf16(al[mt][ks], bh[ks], acc[mt], 0, 0, 0);
            }
        const int idxlo = e0 + myrow;
        #pragma unroll
        for (int mt = 0; mt < 4; ++mt)
            #pragma unroll
            for (int r = 0; r < 4; ++r) {
                const float dist = fmaf(-2.0f, acc[mt][r], nnc);
                if (dist < bd[mt][r]) { bd[mt][r] = dist; bi[mt][r] = idxlo; }
            }
    }

    // reduce over the 16 entry-lanes (xor masks < 16 stay within sample group)
    #pragma unroll
    for (int off = 1; off < 16; off <<= 1)
        #pragma unroll
        for (int mt = 0; mt < 4; ++mt)
            #pragma unroll
            for (int r = 0; r < 4; ++r) {
                const float od = __shfl_xor(bd[mt][r], off, 64);
                const int   oi = __shfl_xor(bi[mt][r], off, 64);
                if (od < bd[mt][r] || (od == bd[mt][r] && oi < bi[mt][r])) {
                    bd[mt][r] = od; bi[mt][r] = oi;
                }
            }
    if (c16 == 0)
        #pragma unroll
        for (int mt = 0; mt < 4; ++mt)
            #pragma unroll
            for (int r = 0; r < 4; ++r) {
                const int row = mt * 16 + q * 4 + r;
                bds[row][wv] = bd[mt][r];
                bis[row][wv] = bi[mt][r];
            }
    __syncthreads();
    if (tid < 64) {
        float best = bds[tid][0];
        int   bidx = bis[tid][0];
        #pragma unroll
        for (int w2 = 1; w2 < 4; ++w2) {
            const float d = bds[tid][w2];
            const int   i2 = bis[tid][w2];
            if (d < best || (d == best && i2 < bidx)) { best = d; bidx = i2; }
        }
        // monotonic float->u32 map (handles negative dists), then (dist,idx) u64 key
        const unsigned f = __float_as_uint(best);
        const unsigned m = (f & 0x80000000u) ? ~f : (f | 0x80000000u);
        const unsigned long long key = ((unsigned long long)m << 32) | (unsigned)bidx;
        atomicMin(&bk[vb.bkoff[ck] + s0 + tid], key);
    }
}

// ---------------- gather zq planes from final keys ----------------
__global__ __launch_bounds__(256) void gather_b(
    const unsigned long long* __restrict__ bk,
    const unsigned short* __restrict__ ch0, const unsigned short* __restrict__ cl0,
    const unsigned short* __restrict__ ch1, const unsigned short* __restrict__ cl1,
    const unsigned short* __restrict__ ch2, const unsigned short* __restrict__ cl2,
    unsigned short* __restrict__ zqh, unsigned short* __restrict__ zql)
{
    const int gid = blockIdx.x * 256 + threadIdx.x;   // 0 .. 3*B*64
    const int l = gid / (BSZ * 64);
    const int r = gid - l * (BSZ * 64);
    const int s = r >> 6, d = r & 63;
    const int idx = (int)(unsigned)(bk[(size_t)l * BSZ + s] & 0xffffffffULL);
    const unsigned short* ch = (l == 0) ? ch0 : (l == 1 ? ch1 : ch2);
    const unsigned short* cl = (l == 0) ? cl0 : (l == 1 ? cl1 : cl2);
    zqh[gid] = ch[(size_t)idx * 64 + d];
    zql[gid] = cl[(size_t)idx * 64 + d];
}

// ---------------- batched losses ----------------
__global__ __launch_bounds__(256) void loss_b(
    const unsigned short* __restrict__ zeh, const unsigned short* __restrict__ zel,
    const unsigned short* __restrict__ zqh, const unsigned short* __restrict__ zql,
    const float* __restrict__ attb, float* __restrict__ vq_out,
    float* __restrict__ commit_out, float inv)
{
    const int l = blockIdx.z;
    const size_t base = (size_t)l * BSZ * 64;
    const float* at = (l > 0) ? attb + (size_t)(l - 1) * BSZ * 64 : nullptr;
    float cs = 0.f, vs = 0.f;
    for (int t = blockIdx.x * 256 + threadIdx.x; t < BSZ * 64; t += gridDim.x * 256) {
        const float e = bf2f(zeh[base + t]) + bf2f(zel[base + t]);
        const float qv = bf2f(zqh[base + t]) + bf2f(zql[base + t]);
        const float dc = e - qv;
        cs += dc * dc;
        const float za = at ? (e + at[t]) : e;
        const float dv = qv - za;
        vs += dv * dv;
    }
    #pragma unroll
    for (int off = 32; off; off >>= 1) {
        cs += __shfl_down(cs, off, 64);
        vs += __shfl_down(vs, off, 64);
    }
    __shared__ float sc[4], sv[4];
    const int lane = threadIdx.x & 63, w = threadIdx.x >> 6;
    if (lane == 0) { sc[w] = cs; sv[w] = vs; }
    __syncthreads();
    if (threadIdx.x == 0) {
        atomicAdd(commit_out, (sc[0] + sc[1] + sc[2] + sc[3]) * inv);
        atomicAdd(vq_out, (sv[0] + sv[1] + sv[2] + sv[3]) * inv);
    }
}

extern "C" void kernel_launch(void* const* d_in, const int* in_sizes, int n_in,
                              void* d_out, int out_size, void* d_ws, size_t ws_size,
                              hipStream_t stream)
{
    const int CB_SIZES[3] = {2048, 4096, 4096};

    // ---- workspace carve-up (256B-aligned segments) ----
    char* wsp = (char*)d_ws;
    auto alloc = [&](size_t bytes) -> void* {
        void* p = wsp; wsp += (bytes + 255) & ~(size_t)255; return p;
    };
    unsigned long long* bk = (unsigned long long*)alloc((size_t)3 * BSZ * 8);
    float* ATT   = (float*)alloc((size_t)2 * BSZ * 64 * 4);
    float* cbn   = (float*)alloc(10240 * 4);
    float* bcomb = (float*)alloc(128 * 4);
    auto u16a = [&](size_t n) -> unsigned short* { return (unsigned short*)alloc(n * 2); };
    unsigned short* XH  = u16a((size_t)3 * BSZ * 512);
    unsigned short* XL  = u16a((size_t)3 * BSZ * 512);
    unsigned short* H1H = u16a((size_t)3 * BSZ * 256);
    unsigned short* H1L = u16a((size_t)3 * BSZ * 256);
    unsigned short* H2H = u16a((size_t)3 * BSZ * 256);
    unsigned short* H2L = u16a((size_t)3 * BSZ * 256);
    unsigned short* ZEH = u16a((size_t)3 * BSZ * 64);
    unsigned short* ZEL = u16a((size_t)3 * BSZ * 64);
    unsigned short* ZQH = u16a((size_t)3 * BSZ * 64);
    unsigned short* ZQL = u16a((size_t)3 * BSZ * 64);
    unsigned short* WCH = u16a(2 * 4096);
    unsigned short* WREG = u16a((size_t)2 * (3 * 425984 + 655360));

    float* out = (float*)d_out;
    float* vq_loss = out + (size_t)3 * BSZ * 512;
    float* commit  = vq_loss + 1;
    hipMemsetAsync(vq_loss, 0, 2 * sizeof(float), stream);
    hipMemsetAsync(bk, 0xFF, (size_t)3 * BSZ * 8, stream);

    // ---- prep descriptor table (x inputs + weights + codebooks) ----
    PrepArgs pa; int pos = 0, ns = 0;
    const unsigned short *ew1h[3], *ew1l[3], *ew2h[3], *ew2l[3], *ew3h[3], *ew3l[3];
    const unsigned short *dw1h[3], *dw1l[3], *dw2h[3], *dw2l[3], *dw3h[3], *dw3l[3];
    const unsigned short *cbh[3], *cbl[3];
    auto add = [&](const float* src, unsigned short* dh, unsigned short* dl, int n) {
        pa.src[ns] = src; pa.dsth[ns] = dh; pa.dstl[ns] = dl; pa.start[ns] = pos;
        pos += n; ns++;
    };
    for (int l = 0; l < 3; ++l)
        add((const float*)d_in[l], XH + (size_t)l * BSZ * 512, XL + (size_t)l * BSZ * 512, BSZ * 512);
    {
        unsigned short* wc = WREG;
        auto addw = [&](const float* src, int n, const unsigned short** ph, const unsigned short** pl) {
            add(src, wc, wc + n, n);
            *ph = wc; *pl = wc + n; wc += 2 * n;
        };
        for (int l = 0; l < 3; ++l) {
            const int base = 3 + 13 * l;
            addw((const float*)d_in[base + 0], 256 * 512, &ew1h[l], &ew1l[l]);
            addw((const float*)d_in[base + 2], 256 * 256, &ew2h[l], &ew2l[l]);
            addw((const float*)d_in[base + 4], 64 * 256,  &ew3h[l], &ew3l[l]);
            addw((const float*)d_in[base + 6], 256 * 64,  &dw1h[l], &dw1l[l]);
            addw((const float*)d_in[base + 8], 256 * 256, &dw2h[l], &dw2l[l]);
            addw((const float*)d_in[base + 10], 512 * 256, &dw3h[l], &dw3l[l]);
            addw((const float*)d_in[base + 12], CB_SIZES[l] * 64, &cbh[l], &cbl[l]);
        }
    }
    pa.nseg = ns;
    for (int i = ns; i < 26; ++i) pa.start[i] = 0x7fffffff;

    hipLaunchKernelGGL(prep_kernel, dim3(pos >> 10), dim3(256), 0, stream, pa);
    hipLaunchKernelGGL(cb_norms3, dim3(40), dim3(256), 0, stream,
                       (const float*)d_in[15], (const float*)d_in[28], (const float*)d_in[41], cbn);
    {
        AttnA aa;
        for (int j = 0; j < 2; ++j) {
            aa.iw[j] = (const float*)d_in[42 + 4 * j];
            aa.ib[j] = (const float*)d_in[42 + 4 * j + 1];
            aa.ow[j] = (const float*)d_in[42 + 4 * j + 2];
            aa.ob[j] = (const float*)d_in[42 + 4 * j + 3];
            aa.wch[j] = WCH + j * 4096;
            aa.bc[j] = bcomb + j * 64;
        }
        hipLaunchKernelGGL(attn_combine, dim3(2), dim3(256), 0, stream, aa);
    }

    GemmB g{};
    // ---- encoders (split-bf16, fp32-grade) ----
    for (int l = 0; l < 3; ++l) {
        g.Ah[l] = XH + (size_t)l * BSZ * 512; g.Al[l] = XL + (size_t)l * BSZ * 512;
        g.Wh[l] = ew1h[l]; g.Wl[l] = ew1l[l];
        g.bias[l] = (const float*)d_in[3 + 13 * l + 1];
        g.Ch[l] = H1H + (size_t)l * BSZ * 256; g.Cl[l] = H1L + (size_t)l * BSZ * 256;
    }
    hipLaunchKernelGGL((gemm4<1, 128, 1>), dim3(2, 128, 3), dim3(256), 0, stream, g, BSZ, 256, 512, 1);
    for (int l = 0; l < 3; ++l) {
        g.Ah[l] = H1H + (size_t)l * BSZ * 256; g.Al[l] = H1L + (size_t)l * BSZ * 256;
        g.Wh[l] = ew2h[l]; g.Wl[l] = ew2l[l];
        g.bias[l] = (const float*)d_in[3 + 13 * l + 3];
        g.Ch[l] = H2H + (size_t)l * BSZ * 256; g.Cl[l] = H2L + (size_t)l * BSZ * 256;
    }
    hipLaunchKernelGGL((gemm4<1, 128, 1>), dim3(2, 128, 3), dim3(256), 0, stream, g, BSZ, 256, 256, 1);
    for (int l = 0; l < 3; ++l) {
        g.Ah[l] = H2H + (size_t)l * BSZ * 256; g.Al[l] = H2L + (size_t)l * BSZ * 256;
        g.Wh[l] = ew3h[l]; g.Wl[l] = ew3l[l];
        g.bias[l] = (const float*)d_in[3 + 13 * l + 5];
        g.Ch[l] = ZEH + (size_t)l * BSZ * 64; g.Cl[l] = ZEL + (size_t)l * BSZ * 64;
    }
    hipLaunchKernelGGL((gemm4<1, 64, 1>), dim3(1, 128, 3), dim3(256), 0, stream, g, BSZ, 64, 256, 0);

    // ---- VQ: 10 chunks of 1024 entries ----
    VqB vb;
    {
        int c = 0;
        for (int l = 0; l < 3; ++l) {
            const int nch = CB_SIZES[l] / 1024;
            const int cb_off = (l == 0) ? 0 : (l == 1 ? 2048 : 6144);
            for (int k = 0; k < nch; ++k, ++c) {
                vb.zh[c] = ZEH + (size_t)l * BSZ * 64;
                vb.zl[c] = ZEL + (size_t)l * BSZ * 64;
                vb.ch[c] = cbh[l]; vb.cl[c] = cbl[l];
                vb.nn[c] = cbn + cb_off;
                vb.ebase[c] = k * 1024;
                vb.bkoff[c] = l * BSZ;
            }
        }
    }
    hipLaunchKernelGGL(vq_sweep, dim3(BSZ / 64, 10), dim3(256), 0, stream, vb, bk);
    hipLaunchKernelGGL(gather_b, dim3(3 * BSZ * 64 / 256), dim3(256), 0, stream,
                       bk, cbh[0], cbl[0], cbh[1], cbl[1], cbh[2], cbl[2], ZQH, ZQL);

    // ---- folded attention (loss-only, plain bf16) ----
    for (int j = 0; j < 3; ++j) {
        const int jj = j < 2 ? j : 1;
        g.Ah[j] = ZQH + (size_t)jj * BSZ * 64; g.Al[j] = g.Ah[j];
        g.Wh[j] = WCH + jj * 4096; g.Wl[j] = g.Wh[j];
        g.bias[j] = bcomb + jj * 64;
        g.Cf[j] = ATT + (size_t)jj * BSZ * 64;
    }
    hipLaunchKernelGGL((gemm4<0, 64, 0>), dim3(1, 128, 2), dim3(256), 0, stream, g, BSZ, 64, 64, 0);

    // ---- losses ----
    hipLaunchKernelGGL(loss_b, dim3(256, 1, 3), dim3(256), 0, stream,
                       ZEH, ZEL, ZQH, ZQL, ATT, vq_loss, commit, 1.0f / (float)(BSZ * 64));

    // ---- decoders (plain bf16, hi planes) ----
    for (int l = 0; l < 3; ++l) {
        g.Ah[l] = ZQH + (size_t)l * BSZ * 64; g.Al[l] = g.Ah[l];
        g.Wh[l] = dw1h[l]; g.Wl[l] = g.Wh[l];
        g.bias[l] = (const float*)d_in[3 + 13 * l + 7];
        g.Ch[l] = H1H + (size_t)l * BSZ * 256;
    }
    hipLaunchKernelGGL((gemm4<0, 128, 2>), dim3(2, 128, 3), dim3(256), 0, stream, g, BSZ, 256, 64, 1);
    for (int l = 0; l < 3; ++l) {
        g.Ah[l] = H1H + (size_t)l * BSZ * 256; g.Al[l] = g.Ah[l];
        g.Wh[l] = dw2h[l]; g.Wl[l] = g.Wh[l];
        g.bias[l] = (const float*)d_in[3 + 13 * l + 9];
        g.Ch[l] = H2H + (size_t)l * BSZ * 256;
    }
    hipLaunchKernelGGL((gemm4<0, 128, 2>), dim3(2, 128, 3), dim3(256), 0, stream, g, BSZ, 256, 256, 1);
    for (int l = 0; l < 3; ++l) {
        g.Ah[l] = H2H + (size_t)l * BSZ * 256; g.Al[l] = g.Ah[l];
        g.Wh[l] = dw3h[l]; g.Wl[l] = g.Wh[l];
        g.bias[l] = (const float*)d_in[3 + 13 * l + 11];
        g.Cf[l] = out + (size_t)l * BSZ * 512;
    }
    hipLaunchKernelGGL((gemm4<0, 128, 0>), dim3(4, 128, 3), dim3(256), 0, stream, g, BSZ, 512, 256, 0);
}